// Round 10
// baseline (63.461 us; speedup 1.0000x reference)
//
#include <hip/hip_runtime.h>

#define F 32
#define Dd 16
#define C 64
#define Kk 8
#define CLIPV (1.0f - 1e-6f)
#define TABSTRIDE 36      // floats per feature: 16 (a,b) pairs + bias + pad
#define K2 2.8853900817779268f  // 2*log2(e): tanh(z)=1-2/(2^(K2*z)+1)
#define NBLK 2048         // 2048 blocks x 64 rows = 131072

typedef short v8s __attribute__((ext_vector_type(8)));
typedef float v4f __attribute__((ext_vector_type(4)));
typedef float v2f __attribute__((ext_vector_type(2)));

__device__ float g_tab[F * TABSTRIDE];  // folded Clenshaw table (written by prep)

static __device__ inline unsigned cvtpk(float lo, float hi) {
    unsigned r;
    asm("v_cvt_pk_bf16_f32 %0, %1, %2" : "=v"(r) : "v"(lo), "v"(hi));
    return r;
}

// LDS-only barrier: wait own ds_writes (lgkmcnt) then s_barrier; no vmcnt
// drain (X prefetch / output stores / coeff loads stay in flight).
#define BAR_LGKM() do {                                          \
    asm volatile("s_waitcnt lgkmcnt(0)" ::: "memory");           \
    __builtin_amdgcn_s_barrier();                                \
    asm volatile("" ::: "memory");                               \
} while (0)

// Fold phases/lcu_weights/sum_scale (and the 2*log2e tanh prescale) into
// per-f Clenshaw tables: K2*z_f(x) = sum_d a_fd T_d(x) + sqrt(1-x^2)*sum b U + fb
// layout g_tab[f*36 + {2d: a_{d+1}, 2d+1: b_{d+1}, 32: fb}]
__global__ void qkan_prep(const float* __restrict__ phases,
                          const float* __restrict__ lcu_w,
                          const float* __restrict__ sscale,
                          const float* __restrict__ sbias) {
    const int idx = threadIdx.x;  // 512 threads = one (f,d) each
    const int f = idx >> 4, d = idx & 15;
    float asum = 0.f;
#pragma unroll
    for (int dd = 0; dd < Dd; ++dd) asum += fabsf(lcu_w[f * Dd + dd]);
    const float sc = K2 * sscale[f] / (asum + 1e-6f);
    float sp, cp;
    __sincosf(phases[d], &sp, &cp);
    const float wv = lcu_w[f * Dd + d];
    g_tab[f * TABSTRIDE + 2 * d]     = sc * wv * cp;   // a_{d+1}
    g_tab[f * TABSTRIDE + 2 * d + 1] = -sc * wv * sp;  // b_{d+1}
    if (d == 0) g_tab[f * TABSTRIDE + 32] = K2 * sbias[f];
}

// r10 structure — built for 32 waves/CU:
//  - 512-thr blocks (8 waves), one 64-row tile per block, LDS exactly 40 KB
//    (4 blocks/CU), __launch_bounds__(512,8) targets VGPR<=64 (8 waves/SIMD)
//  - X staged transposed+XOR-swizzled in LDS (8 KB): writes conflict-free,
//    reads 2-way (free)
//  - phase 1: wave w, pass p=0..3 evaluates feature f=8p+w for all 64 rows
//    (lane=row). Table address is WAVE-UNIFORM -> s_load -> coeffs in SGPRs,
//    zero table VGPRs/LDS traffic.
//  - phase 2: wave w -> class-tile ct=w&3, row-tiles {2*(w>>2), +1}; Bfr
//    (16 VGPR) loaded AFTER phase 1 so phase-1 pressure stays low.
__global__ __launch_bounds__(512, 8) void qkan_kernel(
    const float* __restrict__ X,        // [B,32]
    const float* __restrict__ coeff,    // [64,32,8]
    const float* __restrict__ kbias,    // [64]
    float* __restrict__ out)            // [B,64]
{
    __shared__ float s_xT[F * 64];                // 8192 B, index [f*64 + (row^f)]
    __shared__ unsigned short s_basis[F * 512];   // 32768 B, chunk f: 64 rows x 8 bf16

    const int tid = threadIdx.x;
    const int lane = tid & 63;
    const int wu = __builtin_amdgcn_readfirstlane(tid >> 6);  // 0..7, uniform
    const int h = lane >> 4;
    const int r16 = lane & 15;

    const int rb = blockIdx.x * 64;

    // ---- stage X: 2048 floats, coalesced loads, transposed xor-swizzled writes ----
    {
        const float* xp = X + (size_t)rb * F;
#pragma unroll
        for (int k = 0; k < 4; ++k) {
            const int idx = tid + k * 512;
            const int f = idx & 31;        // == tid & 31
            const int lr = idx >> 5;
            s_xT[f * 64 + (lr ^ f)] = xp[idx];
        }
    }
    BAR_LGKM();

    // ---- phase 1: 4 passes; wave-uniform feature => SGPR coeff table ----
#pragma unroll
    for (int p = 0; p < 4; ++p) {
        const int fu = __builtin_amdgcn_readfirstlane(p * 8 + wu);
        const float* tfp = g_tab + fu * TABSTRIDE;              // uniform -> s_load
        const v2f* tf2 = reinterpret_cast<const v2f*>(tfp);
        const float fb = tfp[32];
        const float x0 = s_xT[fu * 64 + (lane ^ fu)];           // 2-way banks, free
        const float x = fminf(fmaxf(x0, -CLIPV), CLIPV);
        const float s1 = sqrtf(fmaxf(__builtin_fmaf(-x, x, 1.f), 0.f));
        const float tx = x + x;
        const v2f tx2 = {tx, tx};
        // paired Clenshaw: .x = T-chain (coeff a), .y = U-chain (coeff b)
        v2f w = {0.f, 0.f}, wp = {0.f, 0.f};
#pragma unroll
        for (int j = 15; j >= 0; --j) {
            const v2f wn = (tf2[j] - wp) + tx2 * w;  // v_pk_add + v_pk_fma, SGPR coeff
            wp = w;
            w = wn;
        }
        float z = fb - wp[0];
        z = __builtin_fmaf(x, w[0], z);
        z = __builtin_fmaf(s1, w[1], z);
        // tanh via exp2 (K2 pre-folded): t = 1 - 2/(2^z + 1)
        float e;
        asm("v_exp_f32 %0, %1" : "=v"(e) : "v"(z));
        const float rr = __builtin_amdgcn_rcpf(e + 1.f);
        const float t = __builtin_fmaf(-2.f, rr, 1.f);
        // Chebyshev basis T_0..T_7 -> one b128 LDS write (banks uniform: 8/bank)
        const float t2 = t + t;
        const float b1 = t;
        const float b2 = t2 * b1 - 1.f;
        const float b3 = t2 * b2 - b1;
        const float b4 = t2 * b3 - b2;
        const float b5 = t2 * b4 - b3;
        const float b6 = t2 * b5 - b4;
        const float b7 = t2 * b6 - b5;
        uint4 pk;
        pk.x = cvtpk(1.f, b1);
        pk.y = cvtpk(b2, b3);
        pk.z = cvtpk(b4, b5);
        pk.w = cvtpk(b6, b7);
        *reinterpret_cast<uint4*>(&s_basis[fu * 512 + lane * 8]) = pk;
    }
    BAR_LGKM();

    // ---- phase 2: wave wu -> class-tile ct, row-tiles rt0, rt0+1 ----
    // MFMA step q, lane quarter h, regs j hold phys kappa=(4q+h)*8+j,
    // i.e. f=4q+h, cheb-k=j (same lane<->k map on A and B => K-perm invariant)
    const int ct = wu & 3;
    const int rt0 = (wu >> 2) * 2;
    const int cidx = ct * 16 + r16;
    v8s Bfr[8];
#pragma unroll
    for (int q = 0; q < 8; ++q) {
        const float* gp = coeff + ((size_t)(cidx * F + 4 * q + h) * Kk);
        const float4 g0 = *reinterpret_cast<const float4*>(gp);
        const float4 g1 = *reinterpret_cast<const float4*>(gp + 4);
        union { unsigned u[4]; v8s v; } bb;
        bb.u[0] = cvtpk(g0.x, g0.y);
        bb.u[1] = cvtpk(g0.z, g0.w);
        bb.u[2] = cvtpk(g1.x, g1.y);
        bb.u[3] = cvtpk(g1.z, g1.w);
        Bfr[q] = bb.v;
    }
    const float biasreg = kbias[cidx];

#pragma unroll
    for (int j = 0; j < 2; ++j) {
        const int rt = rt0 + j;
        v4f acc = {0.f, 0.f, 0.f, 0.f};
#pragma unroll
        for (int q = 0; q < 8; ++q) {
            const v8s a = *reinterpret_cast<const v8s*>(
                &s_basis[(4 * q + h) * 512 + (rt * 16 + r16) * 8]);
            acc = __builtin_amdgcn_mfma_f32_16x16x32_bf16(a, Bfr[q], acc, 0, 0, 0);
        }
        const int row0 = rb + rt * 16 + h * 4;
#pragma unroll
        for (int i = 0; i < 4; ++i) {
            out[(size_t)(row0 + i) * C + cidx] = acc[i] + biasreg;
        }
    }
}

extern "C" void kernel_launch(void* const* d_in, const int* in_sizes, int n_in,
                              void* d_out, int out_size, void* d_ws, size_t ws_size,
                              hipStream_t stream) {
    const float* X  = (const float*)d_in[0];
    const float* ph = (const float*)d_in[1];
    const float* lw = (const float*)d_in[2];
    const float* ss = (const float*)d_in[3];
    const float* sb = (const float*)d_in[4];
    const float* kc = (const float*)d_in[5];
    const float* kb = (const float*)d_in[6];
    float* out = (float*)d_out;

    qkan_prep<<<dim3(1), dim3(512), 0, stream>>>(ph, lw, ss, sb);
    qkan_kernel<<<dim3(NBLK), dim3(512), 0, stream>>>(X, kc, kb, out);
}

// Round 11
// 40.123 us; speedup vs baseline: 1.5817x; 1.5817x over previous
//
#include <hip/hip_runtime.h>

#define F 32
#define Dd 16
#define C 64
#define Kk 8
#define CLIPV (1.0f - 1e-6f)
#define CHUNKU 536        // ushorts per k-chunk: 64 rows * 8 bf16 + pad -> 1072B (67 16B-slots)
#define K2 2.8853900817779268f  // 2*log2(e): tanh(z)=1-2/(2^(K2*z)+1)
#define NBLK 1024
#define MT 2              // row-tiles of 64 per block
#define REPS 2            // DIAGNOSTIC: run the whole tile loop twice (identical
                          // writes) so the dispatch exceeds the 40us fill kernels
                          // and shows up in rocprof top-5 with full counters.

typedef short v8s __attribute__((ext_vector_type(8)));
typedef float v4f __attribute__((ext_vector_type(4)));
typedef float v2f __attribute__((ext_vector_type(2)));

static __device__ inline unsigned cvtpk(float lo, float hi) {
    unsigned r;
    asm("v_cvt_pk_bf16_f32 %0, %1, %2" : "=v"(r) : "v"(lo), "v"(hi));
    return r;
}

// LDS-only barriers: BAR_WRITES waits own ds_writes (lgkmcnt) then s_barrier;
// BAR_READS is a bare s_barrier (phase-2 ds_reads were all consumed by MFMAs).
// Neither drains vmcnt, so X prefetches / output stores stay in flight.
#define BAR_WRITES() do {                                        \
    asm volatile("s_waitcnt lgkmcnt(0)" ::: "memory");           \
    __builtin_amdgcn_s_barrier();                                \
    asm volatile("" ::: "memory");                               \
} while (0)
#define BAR_READS() do {                                         \
    asm volatile("" ::: "memory");                               \
    __builtin_amdgcn_s_barrier();                                \
    asm volatile("" ::: "memory");                               \
} while (0)

__global__ __launch_bounds__(256, 4) void qkan_kernel(
    const float* __restrict__ X,        // [B,32]
    const float* __restrict__ phases,   // [16]
    const float* __restrict__ lcu_w,    // [32,16]
    const float* __restrict__ sscale,   // [32]
    const float* __restrict__ sbias,    // [32]
    const float* __restrict__ coeff,    // [64,32,8]
    const float* __restrict__ kbias,    // [64]
    float* __restrict__ out)            // [B,64]
{
    __shared__ unsigned short s_basis[F * CHUNKU];   // 34304 B

    const int tid = threadIdx.x;
    const int lane = tid & 63;
    const int wu = __builtin_amdgcn_readfirstlane(tid >> 6);
    const int h = lane >> 4;
    const int r16 = lane & 15;
    const int fe = tid & 31;   // eval feature
    const int rg = tid >> 5;   // eval row-group (8 rows)

    const int rb0 = blockIdx.x * (MT * 64);

    // ---- fold Clenshaw table for feature fe into VGPRs (once per kernel) ----
    // K2*z(x) = sum_d a_d T_d(x) + sqrt(1-x^2) * sum_d b_d U_{d-1}(x) + fbias
    v2f cc[16];
    float fbias;
    {
        const float* lwf = lcu_w + fe * Dd;
        float wv[16];
        float asum = 0.f;
#pragma unroll
        for (int d = 0; d < Dd; ++d) {
            wv[d] = lwf[d];
            asum += fabsf(wv[d]);
        }
        const float sc = K2 * sscale[fe] / (asum + 1e-6f);
#pragma unroll
        for (int d = 0; d < Dd; ++d) {
            float sp, cp;
            __sincosf(phases[d], &sp, &cp);
            cc[d][0] = sc * wv[d] * cp;    // a_{d+1}
            cc[d][1] = -sc * wv[d] * sp;   // b_{d+1}
        }
        fbias = K2 * sbias[fe];
    }

    // ---- B fragments: wave wu owns classes [16wu,16wu+16) ----
    v8s Bfr[8];
    const int cidx = wu * 16 + r16;
#pragma unroll
    for (int q = 0; q < 8; ++q) {
        const float* gp = coeff + ((size_t)(cidx * F + 4 * q + h) * Kk);
        const float4 g0 = *reinterpret_cast<const float4*>(gp);
        const float4 g1 = *reinterpret_cast<const float4*>(gp + 4);
        union { unsigned u[4]; v8s v; } bb;
        bb.u[0] = cvtpk(g0.x, g0.y);
        bb.u[1] = cvtpk(g0.z, g0.w);
        bb.u[2] = cvtpk(g1.x, g1.y);
        bb.u[3] = cvtpk(g1.z, g1.w);
        Bfr[q] = bb.v;
    }
    const float biasreg = kbias[cidx];

    for (int rep = 0; rep < REPS; ++rep) {
        // X prefetch for tile 0 of this rep
        float xq[8];
        {
            const float* xp = X + (size_t)(rb0 + rg * 8) * F + fe;
#pragma unroll
            for (int m = 0; m < 8; ++m) xq[m] = xp[m * F];
        }
        if (rep) BAR_READS();  // rep-1 phase-2 reads consumed before overwrite

        for (int mt = 0; mt < MT; ++mt) {
            const int row_base = rb0 + mt * 64;
            if (mt) BAR_READS();

            // prefetch next tile's X (stays in flight across barriers)
            float xn[8];
            if (mt + 1 < MT) {
                const float* xp = X + (size_t)(row_base + 64 + rg * 8) * F + fe;
#pragma unroll
                for (int m = 0; m < 8; ++m) xn[m] = xp[m * F];
            }

            // ---- phase 1: 8 independent row-evals of feature fe ----
#pragma unroll
            for (int m = 0; m < 8; ++m) {
                const int row = rg * 8 + m;
                const float x = fminf(fmaxf(xq[m], -CLIPV), CLIPV);
                const float s1 = sqrtf(fmaxf(__builtin_fmaf(-x, x, 1.f), 0.f));
                const float tx = x + x;
                const v2f tx2 = {tx, tx};
                v2f w = {0.f, 0.f}, wp = {0.f, 0.f};
#pragma unroll
                for (int j = 15; j >= 0; --j) {
                    const v2f wn = (cc[j] - wp) + tx2 * w;  // v_pk_add + v_pk_fma
                    wp = w;
                    w = wn;
                }
                float z = fbias - wp[0];
                z = __builtin_fmaf(x, w[0], z);
                z = __builtin_fmaf(s1, w[1], z);
                float e;
                asm("v_exp_f32 %0, %1" : "=v"(e) : "v"(z));
                const float rr = __builtin_amdgcn_rcpf(e + 1.f);
                const float t = __builtin_fmaf(-2.f, rr, 1.f);
                const float t2 = t + t;
                const float b1 = t;
                const float b2 = t2 * b1 - 1.f;
                const float b3 = t2 * b2 - b1;
                const float b4 = t2 * b3 - b2;
                const float b5 = t2 * b4 - b3;
                const float b6 = t2 * b5 - b4;
                const float b7 = t2 * b6 - b5;
                uint4 pk;
                pk.x = cvtpk(1.f, b1);
                pk.y = cvtpk(b2, b3);
                pk.z = cvtpk(b4, b5);
                pk.w = cvtpk(b6, b7);
                *reinterpret_cast<uint4*>(&s_basis[fe * CHUNKU + row * 8]) = pk;
            }
            BAR_WRITES();

            // ---- phase 2: MFMA, wave wu -> classes [16wu,16wu+16), 64 rows ----
#pragma unroll
            for (int t = 0; t < 4; ++t) {
                v4f acc = {0.f, 0.f, 0.f, 0.f};
#pragma unroll
                for (int q = 0; q < 8; ++q) {
                    const v8s a = *reinterpret_cast<const v8s*>(
                        &s_basis[(4 * q + h) * CHUNKU + (t * 16 + r16) * 8]);
                    acc = __builtin_amdgcn_mfma_f32_16x16x32_bf16(a, Bfr[q], acc, 0, 0, 0);
                }
                const int row0 = row_base + t * 16 + h * 4;
#pragma unroll
                for (int i = 0; i < 4; ++i) {
                    out[(size_t)(row0 + i) * C + cidx] = acc[i] + biasreg;
                }
            }

            if (mt + 1 < MT) {
#pragma unroll
                for (int m = 0; m < 8; ++m) xq[m] = xn[m];
            }
        }
    }
}

extern "C" void kernel_launch(void* const* d_in, const int* in_sizes, int n_in,
                              void* d_out, int out_size, void* d_ws, size_t ws_size,
                              hipStream_t stream) {
    const float* X  = (const float*)d_in[0];
    const float* ph = (const float*)d_in[1];
    const float* lw = (const float*)d_in[2];
    const float* ss = (const float*)d_in[3];
    const float* sb = (const float*)d_in[4];
    const float* kc = (const float*)d_in[5];
    const float* kb = (const float*)d_in[6];
    float* out = (float*)d_out;
    qkan_kernel<<<dim3(NBLK), dim3(256), 0, stream>>>(X, ph, lw, ss, sb, kc, kb, out);
}

// Round 12
// 27.840 us; speedup vs baseline: 2.2795x; 1.4412x over previous
//
#include <hip/hip_runtime.h>

#define F 32
#define Dd 16
#define C 64
#define Kk 8
#define CLIPV (1.0f - 1e-6f)
#define K2 2.8853900817779268f  // 2*log2(e): tanh(z)=1-2/(2^(K2*z)+1)
#define NBLK 2048               // 2048 blocks x 64 rows = 131072

typedef short v8s __attribute__((ext_vector_type(8)));
typedef float v4f __attribute__((ext_vector_type(4)));
typedef float v2f __attribute__((ext_vector_type(2)));

static __device__ inline unsigned cvtpk(float lo, float hi) {
    unsigned r;
    asm("v_cvt_pk_bf16_f32 %0, %1, %2" : "=v"(r) : "v"(lo), "v"(hi));
    return r;
}

// LDS-only barrier: wait own ds_writes (lgkmcnt) then s_barrier; no vmcnt
// drain (X loads / coeff loads / output stores stay in flight).
#define BAR_WRITES() do {                                        \
    asm volatile("s_waitcnt lgkmcnt(0)" ::: "memory");           \
    __builtin_amdgcn_s_barrier();                                \
    asm volatile("" ::: "memory");                               \
} while (0)

// r12 structure:
//  - ONE 64-row tile per block (MT=1, 2048 blocks): block churn staggers
//    phases across co-resident blocks -> eval(VALU) of one block overlaps
//    MFMA/LDS of another (r11 diagnostic showed phase-locked convoy).
//  - LDS exactly 32 KB (5 blocks/CU resident) via XOR swizzle slot=row^(f&7):
//    conflict-minimal on BOTH the feature-major writes (lanes=features) and
//    the row-major reads (lanes=rows) -- no pad needed.
//  - phase 1: thread (fe=tid&31, rg=tid>>5) evals feature fe for rows
//    rg*8..+7; folded Clenshaw table in VGPRs (zero table loads per eval).
//  - phase 2: wave wu owns classes [16wu,16wu+16), Bfr in VGPRs, one
//    lgkm-only barrier between phases; single barrier per block.
__global__ __launch_bounds__(256, 4) void qkan_kernel(
    const float* __restrict__ X,        // [B,32]
    const float* __restrict__ phases,   // [16]
    const float* __restrict__ lcu_w,    // [32,16]
    const float* __restrict__ sscale,   // [32]
    const float* __restrict__ sbias,    // [32]
    const float* __restrict__ coeff,    // [64,32,8]
    const float* __restrict__ kbias,    // [64]
    float* __restrict__ out)            // [B,64]
{
    __shared__ unsigned short s_basis[F * 512];   // 32768 B exactly

    const int tid = threadIdx.x;
    const int lane = tid & 63;
    const int wu = __builtin_amdgcn_readfirstlane(tid >> 6);
    const int h = lane >> 4;
    const int r16 = lane & 15;
    const int fe = tid & 31;   // eval feature
    const int fe7 = fe & 7;
    const int rg = tid >> 5;   // eval row-group (8 rows)

    const int rb = blockIdx.x * 64;

    // ---- X prefetch: xq[m] = X[rb+rg*8+m][fe] (32-lane coalesced) ----
    float xq[8];
    {
        const float* xp = X + (size_t)(rb + rg * 8) * F + fe;
#pragma unroll
        for (int m = 0; m < 8; ++m) xq[m] = xp[m * F];
    }

    // ---- fold Clenshaw table for feature fe into VGPRs (once per block) ----
    // K2*z(x) = sum_d a_d T_d(x) + sqrt(1-x^2) * sum_d b_d U_{d-1}(x) + fbias
    v2f cc[16];
    float fbias;
    {
        const float* lwf = lcu_w + fe * Dd;
        float wv[16];
        float asum = 0.f;
#pragma unroll
        for (int d = 0; d < Dd; ++d) {
            wv[d] = lwf[d];
            asum += fabsf(wv[d]);
        }
        const float sc = K2 * sscale[fe] / (asum + 1e-6f);
#pragma unroll
        for (int d = 0; d < Dd; ++d) {
            float sp, cp;
            __sincosf(phases[d], &sp, &cp);
            cc[d][0] = sc * wv[d] * cp;    // a_{d+1}
            cc[d][1] = -sc * wv[d] * sp;   // b_{d+1}
        }
        fbias = K2 * sbias[fe];
    }

    // ---- B fragments: wave wu owns classes [16wu,16wu+16) ----
    // MFMA step q, lane quarter h, regs j hold phys kappa=(4q+h)*8+j,
    // i.e. f=4q+h, cheb-k=j (same lane<->k map on A and B => K-perm invariant)
    v8s Bfr[8];
    const int cidx = wu * 16 + r16;
#pragma unroll
    for (int q = 0; q < 8; ++q) {
        const float* gp = coeff + ((size_t)(cidx * F + 4 * q + h) * Kk);
        const float4 g0 = *reinterpret_cast<const float4*>(gp);
        const float4 g1 = *reinterpret_cast<const float4*>(gp + 4);
        union { unsigned u[4]; v8s v; } bb;
        bb.u[0] = cvtpk(g0.x, g0.y);
        bb.u[1] = cvtpk(g0.z, g0.w);
        bb.u[2] = cvtpk(g1.x, g1.y);
        bb.u[3] = cvtpk(g1.z, g1.w);
        Bfr[q] = bb.v;
    }
    const float biasreg = kbias[cidx];

    // ---- phase 1: 8 independent row-evals of feature fe, table in VGPRs ----
    // write slot = row ^ fe7  (row = rg*8+m -> slot = rg*8 + (m^fe7))
#pragma unroll
    for (int m = 0; m < 8; ++m) {
        const float x = fminf(fmaxf(xq[m], -CLIPV), CLIPV);
        const float s1 = sqrtf(fmaxf(__builtin_fmaf(-x, x, 1.f), 0.f));
        const float tx = x + x;
        const v2f tx2 = {tx, tx};
        // paired Clenshaw: .x = T-chain (coeff a), .y = U-chain (coeff b)
        v2f w = {0.f, 0.f}, wp = {0.f, 0.f};
#pragma unroll
        for (int j = 15; j >= 0; --j) {
            const v2f wn = (cc[j] - wp) + tx2 * w;  // v_pk_add + v_pk_fma
            wp = w;
            w = wn;
        }
        float z = fbias - wp[0];
        z = __builtin_fmaf(x, w[0], z);
        z = __builtin_fmaf(s1, w[1], z);
        // tanh via exp2 (K2 pre-folded): t = 1 - 2/(2^z + 1)
        float e;
        asm("v_exp_f32 %0, %1" : "=v"(e) : "v"(z));
        const float rr = __builtin_amdgcn_rcpf(e + 1.f);
        const float t = __builtin_fmaf(-2.f, rr, 1.f);
        // Chebyshev basis T_0..T_7 -> one b128 LDS write (swizzled slot)
        const float t2 = t + t;
        const float b1 = t;
        const float b2 = t2 * b1 - 1.f;
        const float b3 = t2 * b2 - b1;
        const float b4 = t2 * b3 - b2;
        const float b5 = t2 * b4 - b3;
        const float b6 = t2 * b5 - b4;
        const float b7 = t2 * b6 - b5;
        uint4 pk;
        pk.x = cvtpk(1.f, b1);
        pk.y = cvtpk(b2, b3);
        pk.z = cvtpk(b4, b5);
        pk.w = cvtpk(b6, b7);
        *reinterpret_cast<uint4*>(
            &s_basis[fe * 512 + rg * 64 + ((m ^ fe7) << 3)]) = pk;
    }
    BAR_WRITES();  // lgkmcnt(0) only; the single barrier of the kernel

    // ---- phase 2: MFMA, wave wu computes classes [16wu,16wu+16) for 64 rows ----
    // read slot = (t*16+r16) ^ ((4q+h)&7) = (t*16+r16) ^ h ^ ((q&1)<<2)
#pragma unroll
    for (int t = 0; t < 4; ++t) {
        const int s0 = ((t * 16 + r16) ^ h) << 3;  // ushort idx of swizzled slot
        v4f acc = {0.f, 0.f, 0.f, 0.f};
#pragma unroll
        for (int q = 0; q < 8; ++q) {
            const int idx = (4 * q + h) * 512 + (s0 ^ ((q & 1) << 5));
            const v8s a = *reinterpret_cast<const v8s*>(&s_basis[idx]);
            acc = __builtin_amdgcn_mfma_f32_16x16x32_bf16(a, Bfr[q], acc, 0, 0, 0);
        }
        const int row0 = rb + t * 16 + h * 4;
#pragma unroll
        for (int i = 0; i < 4; ++i) {
            out[(size_t)(row0 + i) * C + cidx] = acc[i] + biasreg;
        }
    }
}

extern "C" void kernel_launch(void* const* d_in, const int* in_sizes, int n_in,
                              void* d_out, int out_size, void* d_ws, size_t ws_size,
                              hipStream_t stream) {
    const float* X  = (const float*)d_in[0];
    const float* ph = (const float*)d_in[1];
    const float* lw = (const float*)d_in[2];
    const float* ss = (const float*)d_in[3];
    const float* sb = (const float*)d_in[4];
    const float* kc = (const float*)d_in[5];
    const float* kb = (const float*)d_in[6];
    float* out = (float*)d_out;
    qkan_kernel<<<dim3(NBLK), dim3(256), 0, stream>>>(X, ph, lw, ss, sb, kc, kb, out);
}

// Round 13
// 26.434 us; speedup vs baseline: 2.4007x; 1.0532x over previous
//
#include <hip/hip_runtime.h>

#define F 32
#define Dd 16
#define C 64
#define Kk 8
#define CLIPV (1.0f - 1e-6f)
#define CHUNKU 536        // ushorts per k-chunk: 64 rows * 8 bf16 + pad -> 1072B (67 16B-slots)
#define K2 2.8853900817779268f  // 2*log2(e): tanh(z)=1-2/(2^(K2*z)+1)
#define NBLK 1024
#define MT 2              // row-tiles of 64 per block

typedef short v8s __attribute__((ext_vector_type(8)));
typedef float v4f __attribute__((ext_vector_type(4)));
typedef float v2f __attribute__((ext_vector_type(2)));

static __device__ inline unsigned cvtpk(float lo, float hi) {
    unsigned r;
    asm("v_cvt_pk_bf16_f32 %0, %1, %2" : "=v"(r) : "v"(lo), "v"(hi));
    return r;
}

// Forced VOP3P packed-f32 ops (LLVM does not reliably select v_pk_* for
// generic <2 x float> IR; r11 counters show ~2x the expected VALU issue).
static __device__ inline v2f pk_sub(v2f a, v2f b) {  // a - b
    v2f r;
    asm("v_pk_add_f32 %0, %1, %2 neg_lo:[0,1] neg_hi:[0,1]"
        : "=v"(r) : "v"(a), "v"(b));
    return r;
}
static __device__ inline v2f pk_fma(v2f a, v2f b, v2f c) {  // a*b + c
    v2f r;
    asm("v_pk_fma_f32 %0, %1, %2, %3"
        : "=v"(r) : "v"(a), "v"(b), "v"(c));
    return r;
}

// LDS-only barriers: BAR_WRITES waits own ds_writes (lgkmcnt) then s_barrier;
// BAR_READS is a bare s_barrier (phase-2 ds_reads were all consumed by MFMAs).
// Neither drains vmcnt, so X prefetches / output stores stay in flight.
#define BAR_WRITES() do {                                        \
    asm volatile("s_waitcnt lgkmcnt(0)" ::: "memory");           \
    __builtin_amdgcn_s_barrier();                                \
    asm volatile("" ::: "memory");                               \
} while (0)
#define BAR_READS() do {                                         \
    asm volatile("" ::: "memory");                               \
    __builtin_amdgcn_s_barrier();                                \
    asm volatile("" ::: "memory");                               \
} while (0)

// Structure (r13 = r9 + forced-pk Clenshaw + med3 clamp + raw sqrt):
//  - phase-1 feature-major: thread (fe=tid&31, rg=tid>>5) evaluates feature fe
//    for rows rg*8..rg*8+7; folded Clenshaw table (33 coeffs) lives in VGPRs
//  - phase-2: wave wu owns classes [16wu,16wu+16), Bfr in VGPRs, A-fragments
//    from chunk-major LDS basis (stride 1072B: bank-uniform writes and reads)
__global__ __launch_bounds__(256, 4) void qkan_kernel(
    const float* __restrict__ X,        // [B,32]
    const float* __restrict__ phases,   // [16]
    const float* __restrict__ lcu_w,    // [32,16]
    const float* __restrict__ sscale,   // [32]
    const float* __restrict__ sbias,    // [32]
    const float* __restrict__ coeff,    // [64,32,8]
    const float* __restrict__ kbias,    // [64]
    float* __restrict__ out)            // [B,64]
{
    __shared__ unsigned short s_basis[F * CHUNKU];   // 34304 B

    const int tid = threadIdx.x;
    const int lane = tid & 63;
    const int wu = __builtin_amdgcn_readfirstlane(tid >> 6);
    const int h = lane >> 4;
    const int r16 = lane & 15;
    const int fe = tid & 31;   // eval feature
    const int rg = tid >> 5;   // eval row-group (8 rows)

    const int rb0 = blockIdx.x * (MT * 64);

    // ---- X prefetch for tile 0: xq[m] = X[rb0+rg*8+m][fe] (coalesced) ----
    float xq[8];
    {
        const float* xp = X + (size_t)(rb0 + rg * 8) * F + fe;
#pragma unroll
        for (int m = 0; m < 8; ++m) xq[m] = xp[m * F];
    }

    // ---- fold Clenshaw table for feature fe into VGPRs (once per kernel) ----
    // K2*z(x) = sum_d a_d T_d(x) + sqrt(1-x^2) * sum_d b_d U_{d-1}(x) + fbias
    v2f cc[16];
    float fbias;
    {
        const float* lwf = lcu_w + fe * Dd;
        float wv[16];
        float asum = 0.f;
#pragma unroll
        for (int d = 0; d < Dd; ++d) {
            wv[d] = lwf[d];
            asum += fabsf(wv[d]);
        }
        const float sc = K2 * sscale[fe] / (asum + 1e-6f);
#pragma unroll
        for (int d = 0; d < Dd; ++d) {
            float sp, cp;
            __sincosf(phases[d], &sp, &cp);
            cc[d][0] = sc * wv[d] * cp;    // a_{d+1}
            cc[d][1] = -sc * wv[d] * sp;   // b_{d+1}
        }
        fbias = K2 * sbias[fe];
    }

    // ---- B fragments: wave wu owns classes [16wu,16wu+16) ----
    // MFMA step q, lane quarter h, regs j hold phys kappa=(4q+h)*8+j,
    // i.e. f=4q+h, cheb-k=j (same lane<->k map on A and B => K-perm invariant)
    v8s Bfr[8];
    const int cidx = wu * 16 + r16;
#pragma unroll
    for (int q = 0; q < 8; ++q) {
        const float* gp = coeff + ((size_t)(cidx * F + 4 * q + h) * Kk);
        const float4 g0 = *reinterpret_cast<const float4*>(gp);
        const float4 g1 = *reinterpret_cast<const float4*>(gp + 4);
        union { unsigned u[4]; v8s v; } bb;
        bb.u[0] = cvtpk(g0.x, g0.y);
        bb.u[1] = cvtpk(g0.z, g0.w);
        bb.u[2] = cvtpk(g1.x, g1.y);
        bb.u[3] = cvtpk(g1.z, g1.w);
        Bfr[q] = bb.v;
    }
    const float biasreg = kbias[cidx];

    for (int mt = 0; mt < MT; ++mt) {
        const int row_base = rb0 + mt * 64;
        if (mt) BAR_READS();  // prev phase-2 LDS reads all consumed; no VMEM drain

        // prefetch next tile's X (stays in flight across the barriers)
        float xn[8];
        if (mt + 1 < MT) {
            const float* xp = X + (size_t)(row_base + 64 + rg * 8) * F + fe;
#pragma unroll
            for (int m = 0; m < 8; ++m) xn[m] = xp[m * F];
        }

        // ---- phase 1: 8 independent row-evals of feature fe, table in VGPRs ----
#pragma unroll
        for (int m = 0; m < 8; ++m) {
            const int row = rg * 8 + m;
            const float x = __builtin_amdgcn_fmed3f(xq[m], -CLIPV, CLIPV);
            // 1 - x^2 >= ~1.9e-6 after the clip, so raw hardware sqrt is safe
            const float s1 = __builtin_amdgcn_sqrtf(__builtin_fmaf(-x, x, 1.f));
            const float tx = x + x;
            const v2f tx2 = {tx, tx};
            // paired Clenshaw (forced v_pk_*): .x = T-chain, .y = U-chain
            v2f w = {0.f, 0.f}, wp = {0.f, 0.f};
#pragma unroll
            for (int j = 15; j >= 0; --j) {
                const v2f wn = pk_fma(tx2, w, pk_sub(cc[j], wp));
                wp = w;
                w = wn;
            }
            float z = fbias - wp[0];
            z = __builtin_fmaf(x, w[0], z);
            z = __builtin_fmaf(s1, w[1], z);
            // tanh via exp2 (K2 pre-folded): t = 1 - 2/(2^z + 1)
            float e;
            asm("v_exp_f32 %0, %1" : "=v"(e) : "v"(z));
            const float rr = __builtin_amdgcn_rcpf(e + 1.f);
            const float t = __builtin_fmaf(-2.f, rr, 1.f);
            // Chebyshev basis T_0..T_7 -> one b128 LDS write
            const float t2 = t + t;
            const float b1 = t;
            const float b2 = t2 * b1 - 1.f;
            const float b3 = t2 * b2 - b1;
            const float b4 = t2 * b3 - b2;
            const float b5 = t2 * b4 - b3;
            const float b6 = t2 * b5 - b4;
            const float b7 = t2 * b6 - b5;
            uint4 pk;
            pk.x = cvtpk(1.f, b1);
            pk.y = cvtpk(b2, b3);
            pk.z = cvtpk(b4, b5);
            pk.w = cvtpk(b6, b7);
            *reinterpret_cast<uint4*>(&s_basis[fe * CHUNKU + row * 8]) = pk;
        }
        BAR_WRITES();  // lgkmcnt(0) only: writes visible; X/stores stay in flight

        // ---- phase 2: MFMA, wave wu computes classes [16wu,16wu+16) for 64 rows ----
#pragma unroll
        for (int t = 0; t < 4; ++t) {
            v4f acc = {0.f, 0.f, 0.f, 0.f};
#pragma unroll
            for (int q = 0; q < 8; ++q) {
                const v8s a = *reinterpret_cast<const v8s*>(
                    &s_basis[(4 * q + h) * CHUNKU + (t * 16 + r16) * 8]);
                acc = __builtin_amdgcn_mfma_f32_16x16x32_bf16(a, Bfr[q], acc, 0, 0, 0);
            }
            const int row0 = row_base + t * 16 + h * 4;
#pragma unroll
            for (int i = 0; i < 4; ++i) {
                out[(size_t)(row0 + i) * C + cidx] = acc[i] + biasreg;
            }
        }

        if (mt + 1 < MT) {
#pragma unroll
            for (int m = 0; m < 8; ++m) xq[m] = xn[m];
        }
    }
}

extern "C" void kernel_launch(void* const* d_in, const int* in_sizes, int n_in,
                              void* d_out, int out_size, void* d_ws, size_t ws_size,
                              hipStream_t stream) {
    const float* X  = (const float*)d_in[0];
    const float* ph = (const float*)d_in[1];
    const float* lw = (const float*)d_in[2];
    const float* ss = (const float*)d_in[3];
    const float* sb = (const float*)d_in[4];
    const float* kc = (const float*)d_in[5];
    const float* kb = (const float*)d_in[6];
    float* out = (float*)d_out;
    qkan_kernel<<<dim3(NBLK), dim3(256), 0, stream>>>(X, ph, lw, ss, sb, kc, kb, out);
}

// Round 14
// 26.169 us; speedup vs baseline: 2.4250x; 1.0101x over previous
//
#include <hip/hip_runtime.h>

#define F 32
#define Dd 16
#define C 64
#define Kk 8
#define CLIPV (1.0f - 1e-6f)
#define K2 2.8853900817779268f  // 2*log2(e): tanh(z)=1-2/(2^(K2*z)+1)
#define NBLK 1024
#define MT 2              // row-tiles of 64 per block

typedef short v8s __attribute__((ext_vector_type(8)));
typedef float v4f __attribute__((ext_vector_type(4)));
typedef float v2f __attribute__((ext_vector_type(2)));

static __device__ inline unsigned cvtpk(float lo, float hi) {
    unsigned r;
    asm("v_cvt_pk_bf16_f32 %0, %1, %2" : "=v"(r) : "v"(lo), "v"(hi));
    return r;
}

// Forced VOP3P packed-f32 ops (LLVM does not reliably select v_pk_* for
// generic <2 x float> IR).
static __device__ inline v2f pk_sub(v2f a, v2f b) {  // a - b
    v2f r;
    asm("v_pk_add_f32 %0, %1, %2 neg_lo:[0,1] neg_hi:[0,1]"
        : "=v"(r) : "v"(a), "v"(b));
    return r;
}
static __device__ inline v2f pk_fma(v2f a, v2f b, v2f c) {  // a*b + c
    v2f r;
    asm("v_pk_fma_f32 %0, %1, %2, %3"
        : "=v"(r) : "v"(a), "v"(b), "v"(c));
    return r;
}

// LDS-only barriers: BAR_WRITES waits own ds_writes (lgkmcnt) then s_barrier;
// BAR_READS is a bare s_barrier (phase-2 ds_reads were all consumed by MFMAs).
// Neither drains vmcnt, so X prefetches / output stores stay in flight.
#define BAR_WRITES() do {                                        \
    asm volatile("s_waitcnt lgkmcnt(0)" ::: "memory");           \
    __builtin_amdgcn_s_barrier();                                \
    asm volatile("" ::: "memory");                               \
} while (0)
#define BAR_READS() do {                                         \
    asm volatile("" ::: "memory");                               \
    __builtin_amdgcn_s_barrier();                                \
    asm volatile("" ::: "memory");                               \
} while (0)

// Structure (r14 = r13 + exact-32KB XOR-swizzled basis (5 blocks/CU) + bias
// folded into MFMA C-in):
//  - phase-1 feature-major: thread (fe=tid&31, rg=tid>>5) evaluates feature fe
//    for rows rg*8..rg*8+7; folded Clenshaw table (33 coeffs) lives in VGPRs;
//    forced v_pk_fma/v_pk_add Clenshaw pair
//  - basis LDS 32768 B exactly, swizzle slot=row^(fe&7) (r12-verified):
//    5 blocks/CU resident -> 20 waves/CU (+25% latency hiding vs 16)
//  - phase-2: wave wu owns classes [16wu,16wu+16), Bfr in VGPRs; acc
//    initialized to biasreg so the bias add rides the MFMA C-input
__global__ __launch_bounds__(256, 4) void qkan_kernel(
    const float* __restrict__ X,        // [B,32]
    const float* __restrict__ phases,   // [16]
    const float* __restrict__ lcu_w,    // [32,16]
    const float* __restrict__ sscale,   // [32]
    const float* __restrict__ sbias,    // [32]
    const float* __restrict__ coeff,    // [64,32,8]
    const float* __restrict__ kbias,    // [64]
    float* __restrict__ out)            // [B,64]
{
    __shared__ unsigned short s_basis[F * 512];   // 32768 B exactly

    const int tid = threadIdx.x;
    const int lane = tid & 63;
    const int wu = __builtin_amdgcn_readfirstlane(tid >> 6);
    const int h = lane >> 4;
    const int r16 = lane & 15;
    const int fe = tid & 31;   // eval feature
    const int fe7 = fe & 7;
    const int rg = tid >> 5;   // eval row-group (8 rows)

    const int rb0 = blockIdx.x * (MT * 64);

    // ---- X prefetch for tile 0: xq[m] = X[rb0+rg*8+m][fe] (coalesced) ----
    float xq[8];
    {
        const float* xp = X + (size_t)(rb0 + rg * 8) * F + fe;
#pragma unroll
        for (int m = 0; m < 8; ++m) xq[m] = xp[m * F];
    }

    // ---- fold Clenshaw table for feature fe into VGPRs (once per kernel) ----
    // K2*z(x) = sum_d a_d T_d(x) + sqrt(1-x^2) * sum_d b_d U_{d-1}(x) + fbias
    v2f cc[16];
    float fbias;
    {
        const float* lwf = lcu_w + fe * Dd;
        float wv[16];
        float asum = 0.f;
#pragma unroll
        for (int d = 0; d < Dd; ++d) {
            wv[d] = lwf[d];
            asum += fabsf(wv[d]);
        }
        const float sc = K2 * sscale[fe] / (asum + 1e-6f);
#pragma unroll
        for (int d = 0; d < Dd; ++d) {
            float sp, cp;
            __sincosf(phases[d], &sp, &cp);
            cc[d][0] = sc * wv[d] * cp;    // a_{d+1}
            cc[d][1] = -sc * wv[d] * sp;   // b_{d+1}
        }
        fbias = K2 * sbias[fe];
    }

    // ---- B fragments: wave wu owns classes [16wu,16wu+16) ----
    // MFMA step q, lane quarter h, regs j hold phys kappa=(4q+h)*8+j,
    // i.e. f=4q+h, cheb-k=j (same lane<->k map on A and B => K-perm invariant)
    v8s Bfr[8];
    const int cidx = wu * 16 + r16;
#pragma unroll
    for (int q = 0; q < 8; ++q) {
        const float* gp = coeff + ((size_t)(cidx * F + 4 * q + h) * Kk);
        const float4 g0 = *reinterpret_cast<const float4*>(gp);
        const float4 g1 = *reinterpret_cast<const float4*>(gp + 4);
        union { unsigned u[4]; v8s v; } bb;
        bb.u[0] = cvtpk(g0.x, g0.y);
        bb.u[1] = cvtpk(g0.z, g0.w);
        bb.u[2] = cvtpk(g1.x, g1.y);
        bb.u[3] = cvtpk(g1.z, g1.w);
        Bfr[q] = bb.v;
    }
    const float biasreg = kbias[cidx];

    for (int mt = 0; mt < MT; ++mt) {
        const int row_base = rb0 + mt * 64;
        if (mt) BAR_READS();  // prev phase-2 LDS reads all consumed; no VMEM drain

        // prefetch next tile's X (stays in flight across the barriers)
        float xn[8];
        if (mt + 1 < MT) {
            const float* xp = X + (size_t)(row_base + 64 + rg * 8) * F + fe;
#pragma unroll
            for (int m = 0; m < 8; ++m) xn[m] = xp[m * F];
        }

        // ---- phase 1: 8 independent row-evals of feature fe, table in VGPRs ----
        // swizzled write slot = row ^ fe7  (row = rg*8+m -> rg*8 + (m^fe7))
#pragma unroll
        for (int m = 0; m < 8; ++m) {
            const float x = __builtin_amdgcn_fmed3f(xq[m], -CLIPV, CLIPV);
            // 1 - x^2 >= ~1.9e-6 after the clip, so raw hardware sqrt is safe
            const float s1 = __builtin_amdgcn_sqrtf(__builtin_fmaf(-x, x, 1.f));
            const float tx = x + x;
            const v2f tx2 = {tx, tx};
            // paired Clenshaw (forced v_pk_*): .x = T-chain, .y = U-chain
            v2f w = {0.f, 0.f}, wp = {0.f, 0.f};
#pragma unroll
            for (int j = 15; j >= 0; --j) {
                const v2f wn = pk_fma(tx2, w, pk_sub(cc[j], wp));
                wp = w;
                w = wn;
            }
            float z = fbias - wp[0];
            z = __builtin_fmaf(x, w[0], z);
            z = __builtin_fmaf(s1, w[1], z);
            // tanh via exp2 (K2 pre-folded): t = 1 - 2/(2^z + 1)
            float e;
            asm("v_exp_f32 %0, %1" : "=v"(e) : "v"(z));
            const float rr = __builtin_amdgcn_rcpf(e + 1.f);
            const float t = __builtin_fmaf(-2.f, rr, 1.f);
            // Chebyshev basis T_0..T_7 -> one b128 LDS write (swizzled slot)
            const float t2 = t + t;
            const float b1 = t;
            const float b2 = t2 * b1 - 1.f;
            const float b3 = t2 * b2 - b1;
            const float b4 = t2 * b3 - b2;
            const float b5 = t2 * b4 - b3;
            const float b6 = t2 * b5 - b4;
            const float b7 = t2 * b6 - b5;
            uint4 pk;
            pk.x = cvtpk(1.f, b1);
            pk.y = cvtpk(b2, b3);
            pk.z = cvtpk(b4, b5);
            pk.w = cvtpk(b6, b7);
            *reinterpret_cast<uint4*>(
                &s_basis[fe * 512 + rg * 64 + ((m ^ fe7) << 3)]) = pk;
        }
        BAR_WRITES();  // lgkmcnt(0) only: writes visible; X/stores stay in flight

        // ---- phase 2: MFMA, wave wu computes classes [16wu,16wu+16) for 64 rows ----
        // read slot = (t*16+r16) ^ ((4q+h)&7) -> idx = ((v^h)<<3) ^ ((q&1)<<5)
#pragma unroll
        for (int t = 0; t < 4; ++t) {
            const int s0 = ((t * 16 + r16) ^ h) << 3;
            v4f acc = {biasreg, biasreg, biasreg, biasreg};  // bias via MFMA C-in
#pragma unroll
            for (int q = 0; q < 8; ++q) {
                const int idx = (4 * q + h) * 512 + (s0 ^ ((q & 1) << 5));
                const v8s a = *reinterpret_cast<const v8s*>(&s_basis[idx]);
                acc = __builtin_amdgcn_mfma_f32_16x16x32_bf16(a, Bfr[q], acc, 0, 0, 0);
            }
            const int row0 = row_base + t * 16 + h * 4;
#pragma unroll
            for (int i = 0; i < 4; ++i) {
                out[(size_t)(row0 + i) * C + cidx] = acc[i];
            }
        }

        if (mt + 1 < MT) {
#pragma unroll
            for (int m = 0; m < 8; ++m) xq[m] = xn[m];
        }
    }
}

extern "C" void kernel_launch(void* const* d_in, const int* in_sizes, int n_in,
                              void* d_out, int out_size, void* d_ws, size_t ws_size,
                              hipStream_t stream) {
    const float* X  = (const float*)d_in[0];
    const float* ph = (const float*)d_in[1];
    const float* lw = (const float*)d_in[2];
    const float* ss = (const float*)d_in[3];
    const float* sb = (const float*)d_in[4];
    const float* kc = (const float*)d_in[5];
    const float* kb = (const float*)d_in[6];
    float* out = (float*)d_out;
    qkan_kernel<<<dim3(NBLK), dim3(256), 0, stream>>>(X, ph, lw, ss, sb, kc, kb, out);
}